// Round 5
// baseline (139.801 us; speedup 1.0000x reference)
//
#include <hip/hip_runtime.h>
#include <math.h>

#define N_NODES 8192
#define EDGES   262144
#define D       256
#define ROWCAP  128   // raw in-degree cap (Binomial mean 32, 17-sigma safe)

typedef __attribute__((ext_vector_type(8))) short bf8;    // 8 bf16 in 4 VGPRs
typedef __attribute__((ext_vector_type(4))) float f32x4;  // MFMA accumulator

// ---------------- workspace layout (bytes) ----------------
// 0        : fill    32768     } one 96KB memset (fill + s_src + s_dst)
// 32768    : s_src   32768
// 65536    : s_dst   32768
// 98304    : csr     4194304
// 4292608  : h       8388608   (N x D fp32)
// 12681216 : xhi     4194304   (N x D bf16)
// 16875520 : xlo     4194304
// 21069824 : whi     131072    (D x D bf16)
// 21200896 : wlo     131072
// total 21331968 bytes (~20.3 MB)

__device__ __forceinline__ ushort f2bf(float f) {  // RNE float->bf16
  unsigned u = __float_as_uint(f);
  return (ushort)((u + 0x7FFF + ((u >> 16) & 1)) >> 16);
}
__device__ __forceinline__ float bf2f(ushort s) {
  return __uint_as_float((unsigned)s << 16);
}

// -------- split x and W into bf16 hi/lo planes (x = hi + lo, ~16-bit mantissa) ----
#define XQ 524288   // 8192*256/4
#define WQ 16384    // 256*256/4
__global__ __launch_bounds__(256)
void split_kernel(const float* __restrict__ x, const float* __restrict__ W,
                  ushort* __restrict__ xhi, ushort* __restrict__ xlo,
                  ushort* __restrict__ whi, ushort* __restrict__ wlo) {
  int i = blockIdx.x * 256 + threadIdx.x;   // grid covers XQ+WQ exactly
  const float4* src; ushort *dh, *dl; int j;
  if (i < XQ) { src = (const float4*)x; dh = xhi; dl = xlo; j = i; }
  else        { src = (const float4*)W; dh = whi; dl = wlo; j = i - XQ; }
  float4 v = src[j];
  ushort4 h4, l4;
  h4.x = f2bf(v.x); l4.x = f2bf(v.x - bf2f(h4.x));
  h4.y = f2bf(v.y); l4.y = f2bf(v.y - bf2f(h4.y));
  h4.z = f2bf(v.z); l4.z = f2bf(v.z - bf2f(h4.z));
  h4.w = f2bf(v.w); l4.w = f2bf(v.w - bf2f(h4.w));
  *reinterpret_cast<ushort4*>(dh + (size_t)j * 4) = h4;
  *reinterpret_cast<ushort4*>(dl + (size_t)j * 4) = l4;
}

// -------- h = x @ W^T via split-bf16 MFMA (3 mfma per tile: hh + hl + lh) --------
// Wave owns a 16x64 output strip. A-frag: row=lane&15, k=(lane>>4)*8+[0..8)
// B-frag: col=lane&15, same k (W is (OUT,IN) row-major = k-contiguous = B^T form).
// C/D: col=lane&15, row=(lane>>4)*4+reg  [verified layout, learn_hip m89/m91].
__global__ __launch_bounds__(256)
void gemm_mfma(const ushort* __restrict__ xhi, const ushort* __restrict__ xlo,
               const ushort* __restrict__ whi, const ushort* __restrict__ wlo,
               const float* __restrict__ a_src, const float* __restrict__ a_dst,
               float* __restrict__ h, float* __restrict__ s_src,
               float* __restrict__ s_dst) {
  const int wv = threadIdx.x >> 6, lane = threadIdx.x & 63;
  const int bm = blockIdx.x * 64 + wv * 16;   // gridDim.x = 128
  const int bj = blockIdx.y * 64;             // gridDim.y = 4
  const int r = lane & 15, kg = lane >> 4;
  const f32x4 z4 = {0.f, 0.f, 0.f, 0.f};
  f32x4 acc[4] = {z4, z4, z4, z4};
  const size_t arow = (size_t)(bm + r) * D;
  for (int k0 = 0; k0 < D; k0 += 32) {
    const int ko = k0 + kg * 8;
    bf8 ahi = *reinterpret_cast<const bf8*>(xhi + arow + ko);
    bf8 alo = *reinterpret_cast<const bf8*>(xlo + arow + ko);
#pragma unroll
    for (int ct = 0; ct < 4; ++ct) {
      const size_t boff = (size_t)(bj + ct * 16 + r) * D + ko;
      bf8 bhi = *reinterpret_cast<const bf8*>(whi + boff);
      bf8 blo = *reinterpret_cast<const bf8*>(wlo + boff);
      acc[ct] = __builtin_amdgcn_mfma_f32_16x16x32_bf16(ahi, bhi, acc[ct], 0, 0, 0);
      acc[ct] = __builtin_amdgcn_mfma_f32_16x16x32_bf16(ahi, blo, acc[ct], 0, 0, 0);
      acc[ct] = __builtin_amdgcn_mfma_f32_16x16x32_bf16(alo, bhi, acc[ct], 0, 0, 0);
    }
  }
  // epilogue: store h + fused s_src/s_dst partial dots
  float pS[4] = {0.f, 0.f, 0.f, 0.f}, pD[4] = {0.f, 0.f, 0.f, 0.f};
#pragma unroll
  for (int ct = 0; ct < 4; ++ct) {
    const int col = bj + ct * 16 + r;
    const float av = a_src[col], dv = a_dst[col];
#pragma unroll
    for (int reg = 0; reg < 4; ++reg) {
      const float c = acc[ct][reg];
      h[(size_t)(bm + kg * 4 + reg) * D + col] = c;
      pS[reg] = fmaf(c, av, pS[reg]);
      pD[reg] = fmaf(c, dv, pD[reg]);
    }
  }
#pragma unroll
  for (int reg = 0; reg < 4; ++reg) {
    float ps = pS[reg], pd = pD[reg];
#pragma unroll
    for (int off = 1; off < 16; off <<= 1) {   // reduce over the 16-lane col group
      ps += __shfl_xor(ps, off, 64);
      pd += __shfl_xor(pd, off, 64);
    }
    if (r == 0) {
      atomicAdd(&s_src[bm + kg * 4 + reg], ps);
      atomicAdd(&s_dst[bm + kg * 4 + reg], pd);
    }
  }
}

// -------- scatter raw edges into per-dst buckets (no dedup here) --------
__global__ __launch_bounds__(256)
void scatter_kernel(const int* __restrict__ ei, int* __restrict__ fill,
                    int* __restrict__ csr) {
  int lane = threadIdx.x & 63;
  unsigned long long b = __ballot(ei[lane * 2 + 1] == 0);
  int is64 = (b == 0xFFFFFFFFFFFFFFFFull) ? 1 : 0;
  int e = blockIdx.x * 256 + threadIdx.x;   // grid exactly covers EDGES
  int src, dst;
  if (is64) { src = ei[2 * e];  dst = ei[2 * (EDGES + e)]; }
  else      { src = ei[e];      dst = ei[EDGES + e]; }
  int p = atomicAdd(&fill[dst], 1);
  if (p < ROWCAP) csr[dst * ROWCAP + p] = src;
}

// -------- per-row (one WAVE per row): dedup -> softmax -> SpMM -> ELU+res -> LN --------
__global__ __launch_bounds__(256)
void row_fused(const float* __restrict__ h, const float* __restrict__ s_src,
               const float* __restrict__ s_dst, const int* __restrict__ fill,
               const int* __restrict__ csr, const float* __restrict__ gamma,
               const float* __restrict__ beta, float* __restrict__ out) {
  __shared__ int   s_idx[4][ROWCAP];
  __shared__ float s_w[4][ROWCAP];
  const int w    = threadIdx.x >> 6;       // wave id 0..3
  const int lane = threadIdx.x & 63;
  const int row  = blockIdx.x * 4 + w;
  int len = fill[row];
  if (len > ROWCAP) len = ROWCAP;
  const int len_pad = (len + 7) & ~7;      // pad to 8 for deep-unrolled SpMM
  const float sd = s_dst[row];

  for (int i = lane; i < len; i += 64) s_idx[w][i] = csr[row * ROWCAP + i];
  __syncthreads();

  float lmax = -3.0e38f;
  for (int i = lane; i < len; i += 64) {
    int s = s_idx[w][i];
    bool dup = false;
    for (int j = 0; j < i; ++j)
      if (s_idx[w][j] == s) { dup = true; break; }
    float v;
    if (dup) {
      v = -3.0e38f;
    } else {
      v = s_src[s] + sd;
      v = (v >= 0.f) ? v : 0.2f * v;      // leaky_relu 0.2
      if (v == 0.0f) v = -3.0e38f;        // (attn == 0) * -1e9 mask
    }
    s_w[w][i] = v;
    lmax = fmaxf(lmax, v);
  }
#pragma unroll
  for (int off = 32; off; off >>= 1) lmax = fmaxf(lmax, __shfl_xor(lmax, off, 64));

  float lsum = 0.f;
  for (int i = lane; i < len; i += 64) {
    float e = expf(s_w[w][i] - lmax);
    s_w[w][i] = e;
    lsum += e;
  }
#pragma unroll
  for (int off = 32; off; off >>= 1) lsum += __shfl_xor(lsum, off, 64);
  float inv = (lsum > 0.f) ? (1.0f / lsum) : 0.f;
  for (int i = lane; i < len; i += 64) {
    float ww = s_w[w][i] * inv;
    s_w[w][i] = (ww > 1e-6f) ? ww : 0.f;  // attn * (attn > 1e-6)
  }
  for (int i = len + lane; i < len_pad; i += 64) { s_w[w][i] = 0.f; s_idx[w][i] = 0; }
  __syncthreads();

  // SpMM: lane owns 4 columns (float4); 8 independent gathers in flight
  float4 acc = make_float4(0.f, 0.f, 0.f, 0.f);
  for (int i = 0; i < len_pad; i += 8) {
    float wg[8]; float4 hv[8];
#pragma unroll
    for (int u = 0; u < 8; ++u) {
      wg[u] = s_w[w][i + u];
      hv[u] = *reinterpret_cast<const float4*>(&h[(size_t)s_idx[w][i + u] * D + lane * 4]);
    }
#pragma unroll
    for (int u = 0; u < 8; ++u) {
      acc.x = fmaf(wg[u], hv[u].x, acc.x);
      acc.y = fmaf(wg[u], hv[u].y, acc.y);
      acc.z = fmaf(wg[u], hv[u].z, acc.z);
      acc.w = fmaf(wg[u], hv[u].w, acc.w);
    }
  }

  // ELU + residual
  const float4 hr = *reinterpret_cast<const float4*>(&h[(size_t)row * D + lane * 4]);
  float4 z;
  z.x = ((acc.x > 0.f) ? acc.x : expm1f(acc.x)) + hr.x;
  z.y = ((acc.y > 0.f) ? acc.y : expm1f(acc.y)) + hr.y;
  z.z = ((acc.z > 0.f) ? acc.z : expm1f(acc.z)) + hr.z;
  z.w = ((acc.w > 0.f) ? acc.w : expm1f(acc.w)) + hr.w;

  // LayerNorm over 256 cols within the wave (biased var, eps 1e-5)
  float s1 = z.x + z.y + z.z + z.w;
#pragma unroll
  for (int off = 32; off; off >>= 1) s1 += __shfl_xor(s1, off, 64);
  float mean = s1 * (1.0f / 256.0f);
  float dx = z.x - mean, dy = z.y - mean, dz = z.z - mean, dw = z.w - mean;
  float s2 = dx * dx + dy * dy + dz * dz + dw * dw;
#pragma unroll
  for (int off = 32; off; off >>= 1) s2 += __shfl_xor(s2, off, 64);
  float rs = rsqrtf(s2 * (1.0f / 256.0f) + 1e-5f);

  const float4 gm = *reinterpret_cast<const float4*>(&gamma[lane * 4]);
  const float4 bt = *reinterpret_cast<const float4*>(&beta[lane * 4]);
  float4 o;
  o.x = gm.x * dx * rs + bt.x;
  o.y = gm.y * dy * rs + bt.y;
  o.z = gm.z * dz * rs + bt.z;
  o.w = gm.w * dw * rs + bt.w;
  *reinterpret_cast<float4*>(&out[(size_t)row * D + lane * 4]) = o;
}

extern "C" void kernel_launch(void* const* d_in, const int* in_sizes, int n_in,
                              void* d_out, int out_size, void* d_ws, size_t ws_size,
                              hipStream_t stream) {
  const float* x     = (const float*)d_in[0];
  const int*   ei    = (const int*)d_in[1];
  const float* W     = (const float*)d_in[2];
  const float* a_src = (const float*)d_in[3];
  const float* a_dst = (const float*)d_in[4];
  const float* gamma = (const float*)d_in[5];
  const float* beta  = (const float*)d_in[6];
  float* out = (float*)d_out;

  char* ws = (char*)d_ws;
  int*    fill  = (int*)(ws);
  float*  s_src = (float*)(ws + 32768);
  float*  s_dst = (float*)(ws + 65536);
  int*    csr   = (int*)(ws + 98304);
  float*  h     = (float*)(ws + 4292608);
  ushort* xhi   = (ushort*)(ws + 12681216);
  ushort* xlo   = (ushort*)(ws + 16875520);
  ushort* whi   = (ushort*)(ws + 21069824);
  ushort* wlo   = (ushort*)(ws + 21200896);
  if (ws_size < 21331968) return;  // workspace too small (not expected)

  hipMemsetAsync(ws, 0, 98304, stream);   // fill + s_src + s_dst
  split_kernel<<<(XQ + WQ) / 256, 256, 0, stream>>>(x, W, xhi, xlo, whi, wlo);
  scatter_kernel<<<EDGES / 256, 256, 0, stream>>>(ei, fill, csr);
  gemm_mfma<<<dim3(N_NODES / 64, D / 64), 256, 0, stream>>>(xhi, xlo, whi, wlo,
                                                            a_src, a_dst, h, s_src, s_dst);
  row_fused<<<N_NODES / 4, 256, 0, stream>>>(h, s_src, s_dst, fill, csr, gamma, beta, out);
}

// Round 7
// 126.754 us; speedup vs baseline: 1.1029x; 1.1029x over previous
//
#include <hip/hip_runtime.h>
#include <math.h>

#define N_NODES 8192
#define EDGES   262144
#define D       256
#define ROWCAP  128   // raw in-degree cap (Binomial mean 32, 17-sigma safe)

typedef __attribute__((ext_vector_type(8))) short bf8;    // 8 bf16 in 4 VGPRs
typedef __attribute__((ext_vector_type(4))) float f32x4;  // MFMA accumulator

// ---------------- workspace layout (bytes) ----------------
// 0        : fill    32768     } one 96KB memset (fill + s_src + s_dst)
// 32768    : s_src   32768
// 65536    : s_dst   32768
// 98304    : csr     4194304
// 4292608  : h       8388608   (N x D fp32: residual + LN source)
// 12681216 : h_bf    4194304   (N x D bf16: SpMM gather source, L2-resident)
// 16875520 : whi     131072    (D x D bf16)
// 17006592 : wlo     131072
// total 17137664 bytes (~16.3 MB)

__device__ __forceinline__ ushort f2bf(float f) {  // RNE float->bf16
  unsigned u = __float_as_uint(f);
  return (ushort)((u + 0x7FFF + ((u >> 16) & 1)) >> 16);
}
__device__ __forceinline__ float bf2f(ushort s) {
  return __uint_as_float((unsigned)s << 16);
}

// -------- split W into bf16 hi/lo planes (tiny: 16384 float4s) --------
__global__ __launch_bounds__(256)
void split_w(const float* __restrict__ W, ushort* __restrict__ whi,
             ushort* __restrict__ wlo) {
  int i = blockIdx.x * 256 + threadIdx.x;   // grid covers 16384 exactly
  float4 v = reinterpret_cast<const float4*>(W)[i];
  ushort4 h4, l4;
  h4.x = f2bf(v.x); l4.x = f2bf(v.x - bf2f(h4.x));
  h4.y = f2bf(v.y); l4.y = f2bf(v.y - bf2f(h4.y));
  h4.z = f2bf(v.z); l4.z = f2bf(v.z - bf2f(h4.z));
  h4.w = f2bf(v.w); l4.w = f2bf(v.w - bf2f(h4.w));
  *reinterpret_cast<ushort4*>(whi + (size_t)i * 4) = h4;
  *reinterpret_cast<ushort4*>(wlo + (size_t)i * 4) = l4;
}

// -------- h = x @ W^T via split-bf16 MFMA; x converted in-register --------
// Wave tile: 32 rows (2 strips of 16) x 64 cols (4 ct). Block = 4 waves = 128 rows.
// A-frag: row=lane&15, k=(lane>>4)*8+[0..8) ; B-frag: col=lane&15, same k.
// C/D: col=lane&15, row=(lane>>4)*4+reg  [layout verified on HW, rounds 4-5].
__global__ __launch_bounds__(256, 1)
void gemm_mfma(const float* __restrict__ x,
               const ushort* __restrict__ whi, const ushort* __restrict__ wlo,
               const float* __restrict__ a_src, const float* __restrict__ a_dst,
               float* __restrict__ h, ushort* __restrict__ h_bf,
               float* __restrict__ s_src, float* __restrict__ s_dst) {
  const int wv = threadIdx.x >> 6, lane = threadIdx.x & 63;
  const int bm = blockIdx.x * 128 + wv * 32;   // gridDim.x = 64
  const int bj = blockIdx.y * 64;              // gridDim.y = 4
  const int r = lane & 15, kg = lane >> 4;

  // load + split A fragments for 2 row-strips, all 8 k-tiles (held in regs)
  bf8 ahi[2][8], alo[2][8];
#pragma unroll
  for (int s = 0; s < 2; ++s) {
    const float* xr = x + (size_t)(bm + s * 16 + r) * D;
#pragma unroll
    for (int k0 = 0; k0 < 8; ++k0) {
      float4 v0 = *reinterpret_cast<const float4*>(xr + k0 * 32 + kg * 8);
      float4 v1 = *reinterpret_cast<const float4*>(xr + k0 * 32 + kg * 8 + 4);
      float f[8] = {v0.x, v0.y, v0.z, v0.w, v1.x, v1.y, v1.z, v1.w};
      bf8 hi, lo;
#pragma unroll
      for (int j = 0; j < 8; ++j) {
        ushort hh = f2bf(f[j]);
        hi[j] = (short)hh;
        lo[j] = (short)f2bf(f[j] - bf2f(hh));
      }
      ahi[s][k0] = hi; alo[s][k0] = lo;
    }
  }

  const f32x4 z4 = {0.f, 0.f, 0.f, 0.f};
  f32x4 acc[2][4] = {{z4, z4, z4, z4}, {z4, z4, z4, z4}};
#pragma unroll
  for (int k0 = 0; k0 < 8; ++k0) {
#pragma unroll
    for (int ct = 0; ct < 4; ++ct) {
      const size_t boff = (size_t)(bj + ct * 16 + r) * D + k0 * 32 + kg * 8;
      bf8 bhi = *reinterpret_cast<const bf8*>(whi + boff);
      bf8 blo = *reinterpret_cast<const bf8*>(wlo + boff);
#pragma unroll
      for (int s = 0; s < 2; ++s) {
        acc[s][ct] = __builtin_amdgcn_mfma_f32_16x16x32_bf16(ahi[s][k0], bhi, acc[s][ct], 0, 0, 0);
        acc[s][ct] = __builtin_amdgcn_mfma_f32_16x16x32_bf16(ahi[s][k0], blo, acc[s][ct], 0, 0, 0);
        acc[s][ct] = __builtin_amdgcn_mfma_f32_16x16x32_bf16(alo[s][k0], bhi, acc[s][ct], 0, 0, 0);
      }
    }
  }

  // epilogue: store h (fp32 + bf16) + fused s_src/s_dst partial dots
  float pS[2][4] = {{0.f}}, pD[2][4] = {{0.f}};
#pragma unroll
  for (int s = 0; s < 2; ++s) {
#pragma unroll
    for (int ct = 0; ct < 4; ++ct) {
      const int col = bj + ct * 16 + r;
      const float av = a_src[col], dv = a_dst[col];
#pragma unroll
      for (int reg = 0; reg < 4; ++reg) {
        const float c = acc[s][ct][reg];
        const size_t off = (size_t)(bm + s * 16 + kg * 4 + reg) * D + col;
        h[off] = c;
        h_bf[off] = f2bf(c);
        pS[s][reg] = fmaf(c, av, pS[s][reg]);
        pD[s][reg] = fmaf(c, dv, pD[s][reg]);
      }
    }
  }
#pragma unroll
  for (int s = 0; s < 2; ++s)
#pragma unroll
    for (int reg = 0; reg < 4; ++reg) {
      float ps = pS[s][reg], pd = pD[s][reg];
#pragma unroll
      for (int off = 1; off < 16; off <<= 1) {   // reduce over 16-lane col group
        ps += __shfl_xor(ps, off, 64);
        pd += __shfl_xor(pd, off, 64);
      }
      if (r == 0) {
        atomicAdd(&s_src[bm + s * 16 + kg * 4 + reg], ps);
        atomicAdd(&s_dst[bm + s * 16 + kg * 4 + reg], pd);
      }
    }
}

// -------- scatter raw edges into per-dst buckets (no dedup here) --------
__global__ __launch_bounds__(256)
void scatter_kernel(const int* __restrict__ ei, int* __restrict__ fill,
                    int* __restrict__ csr) {
  int lane = threadIdx.x & 63;
  unsigned long long b = __ballot(ei[lane * 2 + 1] == 0);
  int is64 = (b == 0xFFFFFFFFFFFFFFFFull) ? 1 : 0;
  int e = blockIdx.x * 256 + threadIdx.x;   // grid exactly covers EDGES
  int src, dst;
  if (is64) { src = ei[2 * e];  dst = ei[2 * (EDGES + e)]; }
  else      { src = ei[e];      dst = ei[EDGES + e]; }
  int p = atomicAdd(&fill[dst], 1);
  if (p < ROWCAP) csr[dst * ROWCAP + p] = src;
}

// -------- per-row (one WAVE per row): dedup -> softmax -> SpMM -> ELU+res -> LN --------
__global__ __launch_bounds__(256)
void row_fused(const float* __restrict__ h, const ushort* __restrict__ h_bf,
               const float* __restrict__ s_src, const float* __restrict__ s_dst,
               const int* __restrict__ fill, const int* __restrict__ csr,
               const float* __restrict__ gamma, const float* __restrict__ beta,
               float* __restrict__ out) {
  __shared__ int   s_idx[4][ROWCAP];
  __shared__ float s_w[4][ROWCAP];
  const int w    = threadIdx.x >> 6;       // wave id 0..3
  const int lane = threadIdx.x & 63;
  const int row  = blockIdx.x * 4 + w;
  int len = fill[row];
  if (len > ROWCAP) len = ROWCAP;
  const int len_pad = (len + 7) & ~7;      // pad to 8 for deep-unrolled SpMM
  const float sd = s_dst[row];

  for (int i = lane; i < len; i += 64) s_idx[w][i] = csr[row * ROWCAP + i];
  __syncthreads();

  float lmax = -3.0e38f;
  for (int i = lane; i < len; i += 64) {
    int s = s_idx[w][i];
    bool dup = false;
    for (int j = 0; j < i; ++j)
      if (s_idx[w][j] == s) { dup = true; break; }
    float v;
    if (dup) {
      v = -3.0e38f;
    } else {
      v = s_src[s] + sd;
      v = (v >= 0.f) ? v : 0.2f * v;      // leaky_relu 0.2
      if (v == 0.0f) v = -3.0e38f;        // (attn == 0) * -1e9 mask
    }
    s_w[w][i] = v;
    lmax = fmaxf(lmax, v);
  }
#pragma unroll
  for (int off = 32; off; off >>= 1) lmax = fmaxf(lmax, __shfl_xor(lmax, off, 64));

  float lsum = 0.f;
  for (int i = lane; i < len; i += 64) {
    float e = expf(s_w[w][i] - lmax);
    s_w[w][i] = e;
    lsum += e;
  }
#pragma unroll
  for (int off = 32; off; off >>= 1) lsum += __shfl_xor(lsum, off, 64);
  float inv = (lsum > 0.f) ? (1.0f / lsum) : 0.f;
  for (int i = lane; i < len; i += 64) {
    float ww = s_w[w][i] * inv;
    s_w[w][i] = (ww > 1e-6f) ? ww : 0.f;  // attn * (attn > 1e-6)
  }
  for (int i = len + lane; i < len_pad; i += 64) { s_w[w][i] = 0.f; s_idx[w][i] = 0; }
  __syncthreads();

  // SpMM over bf16 h (L2-resident): lane owns 4 cols; 8 gathers in flight
  float4 acc = make_float4(0.f, 0.f, 0.f, 0.f);
  for (int i = 0; i < len_pad; i += 8) {
    float wg[8]; ushort4 qv[8];
#pragma unroll
    for (int u = 0; u < 8; ++u) {
      wg[u] = s_w[w][i + u];
      qv[u] = *reinterpret_cast<const ushort4*>(h_bf + (size_t)s_idx[w][i + u] * D + lane * 4);
    }
#pragma unroll
    for (int u = 0; u < 8; ++u) {
      acc.x = fmaf(wg[u], bf2f(qv[u].x), acc.x);
      acc.y = fmaf(wg[u], bf2f(qv[u].y), acc.y);
      acc.z = fmaf(wg[u], bf2f(qv[u].z), acc.z);
      acc.w = fmaf(wg[u], bf2f(qv[u].w), acc.w);
    }
  }

  // ELU + residual (fp32 h)
  const float4 hr = *reinterpret_cast<const float4*>(&h[(size_t)row * D + lane * 4]);
  float4 z;
  z.x = ((acc.x > 0.f) ? acc.x : expm1f(acc.x)) + hr.x;
  z.y = ((acc.y > 0.f) ? acc.y : expm1f(acc.y)) + hr.y;
  z.z = ((acc.z > 0.f) ? acc.z : expm1f(acc.z)) + hr.z;
  z.w = ((acc.w > 0.f) ? acc.w : expm1f(acc.w)) + hr.w;

  // LayerNorm over 256 cols within the wave (biased var, eps 1e-5)
  float s1 = z.x + z.y + z.z + z.w;
#pragma unroll
  for (int off = 32; off; off >>= 1) s1 += __shfl_xor(s1, off, 64);
  float mean = s1 * (1.0f / 256.0f);
  float dx = z.x - mean, dy = z.y - mean, dz = z.z - mean, dw = z.w - mean;
  float s2 = dx * dx + dy * dy + dz * dz + dw * dw;
#pragma unroll
  for (int off = 32; off; off >>= 1) s2 += __shfl_xor(s2, off, 64);
  float rs = rsqrtf(s2 * (1.0f / 256.0f) + 1e-5f);

  const float4 gm = *reinterpret_cast<const float4*>(&gamma[lane * 4]);
  const float4 bt = *reinterpret_cast<const float4*>(&beta[lane * 4]);
  float4 o;
  o.x = gm.x * dx * rs + bt.x;
  o.y = gm.y * dy * rs + bt.y;
  o.z = gm.z * dz * rs + bt.z;
  o.w = gm.w * dw * rs + bt.w;
  *reinterpret_cast<float4*>(&out[(size_t)row * D + lane * 4]) = o;
}

extern "C" void kernel_launch(void* const* d_in, const int* in_sizes, int n_in,
                              void* d_out, int out_size, void* d_ws, size_t ws_size,
                              hipStream_t stream) {
  const float* x     = (const float*)d_in[0];
  const int*   ei    = (const int*)d_in[1];
  const float* W     = (const float*)d_in[2];
  const float* a_src = (const float*)d_in[3];
  const float* a_dst = (const float*)d_in[4];
  const float* gamma = (const float*)d_in[5];
  const float* beta  = (const float*)d_in[6];
  float* out = (float*)d_out;

  char* ws = (char*)d_ws;
  int*    fill  = (int*)(ws);
  float*  s_src = (float*)(ws + 32768);
  float*  s_dst = (float*)(ws + 65536);
  int*    csr   = (int*)(ws + 98304);
  float*  h     = (float*)(ws + 4292608);
  ushort* h_bf  = (ushort*)(ws + 12681216);
  ushort* whi   = (ushort*)(ws + 16875520);
  ushort* wlo   = (ushort*)(ws + 17006592);
  if (ws_size < 17137664) return;  // workspace too small (not expected)

  hipMemsetAsync(ws, 0, 98304, stream);   // fill + s_src + s_dst
  split_w<<<64, 256, 0, stream>>>(W, whi, wlo);
  scatter_kernel<<<EDGES / 256, 256, 0, stream>>>(ei, fill, csr);
  gemm_mfma<<<dim3(N_NODES / 128, D / 64), 256, 0, stream>>>(x, whi, wlo,
                                                             a_src, a_dst, h, h_bf,
                                                             s_src, s_dst);
  row_fused<<<N_NODES / 4, 256, 0, stream>>>(h, h_bf, s_src, s_dst, fill, csr,
                                             gamma, beta, out);
}